// Round 5
// baseline (18.096 us; speedup 1.0000x reference)
//
#include <hip/hip_runtime.h>

#define DIM 128
#define TPB 256
#define CLIPV 6.0f

// One 8-lane group = pos pair g (1 dot) + neg bundle g (5 dots sharing the
// center u-row, since negu = repeat(posv,5) structurally). lane covers 16
// elems (4 float4) of each 128-dim row. No grid-stride loop: exactly
// ceil(n_pos/32) blocks x 32 groups.
__global__ void __launch_bounds__(TPB) sg_fused_partial(
    const float* __restrict__ u_emb,
    const float* __restrict__ v_emb,
    const int*  __restrict__ nodes,
    const int*  __restrict__ posu,
    const int*  __restrict__ posv,
    const int*  __restrict__ negu,
    const int*  __restrict__ negv,
    int n_pos,
    float* __restrict__ partial)
{
    const int lane = threadIdx.x & 7;        // 0..7 within group
    const int grp  = threadIdx.x >> 3;       // 0..31 groups per block
    const int g    = blockIdx.x * 32 + grp;  // pos-pair id == neg-bundle id

    float acc = 0.0f;
    if (g < n_pos) {
        // --- indices (broadcast within group; distinct across groups) ---
        const int iu = posu[g];
        const int iv = posv[g];
        const int ic = negu[5 * g];          // neg-bundle center (== posv[g])
        const int nu = nodes[iu];
        const int nv = nodes[iv];
        const int nc = nodes[ic];
        int nn[5];
#pragma unroll
        for (int k = 0; k < 5; ++k) nn[k] = nodes[negv[5 * g + k]];

        const int off = lane * 16;           // 16 floats per lane
        const float4* pa = reinterpret_cast<const float4*>(u_emb + (unsigned)nu * DIM + off);
        const float4* pb = reinterpret_cast<const float4*>(v_emb + (unsigned)nv * DIM + off);
        const float4* pc = reinterpret_cast<const float4*>(u_emb + (unsigned)nc * DIM + off);

        float4 a[4], b[4], c[4], d[5][4];
#pragma unroll
        for (int j = 0; j < 4; ++j) { a[j] = pa[j]; b[j] = pb[j]; c[j] = pc[j]; }
#pragma unroll
        for (int k = 0; k < 5; ++k) {
            const float4* pd = reinterpret_cast<const float4*>(
                v_emb + (unsigned)nn[k] * DIM + off);
#pragma unroll
            for (int j = 0; j < 4; ++j) d[k][j] = pd[j];
        }

        // --- 6 partial dots (all static indexing; stays in VGPRs) ---
        float sp = 0.0f;
        float sn0 = 0.0f, sn1 = 0.0f, sn2 = 0.0f, sn3 = 0.0f, sn4 = 0.0f;
#pragma unroll
        for (int j = 0; j < 4; ++j) {
            sp  += a[j].x * b[j].x + a[j].y * b[j].y + a[j].z * b[j].z + a[j].w * b[j].w;
            sn0 += c[j].x * d[0][j].x + c[j].y * d[0][j].y + c[j].z * d[0][j].z + c[j].w * d[0][j].w;
            sn1 += c[j].x * d[1][j].x + c[j].y * d[1][j].y + c[j].z * d[1][j].z + c[j].w * d[1][j].w;
            sn2 += c[j].x * d[2][j].x + c[j].y * d[2][j].y + c[j].z * d[2][j].z + c[j].w * d[2][j].w;
            sn3 += c[j].x * d[3][j].x + c[j].y * d[3][j].y + c[j].z * d[3][j].z + c[j].w * d[3][j].w;
            sn4 += c[j].x * d[4][j].x + c[j].y * d[4][j].y + c[j].z * d[4][j].z + c[j].w * d[4][j].w;
        }

        // --- 8-lane butterfly for each of the 6 sums ---
#pragma unroll
        for (int m = 1; m <= 4; m <<= 1) {
            sp  += __shfl_xor(sp,  m);
            sn0 += __shfl_xor(sn0, m);
            sn1 += __shfl_xor(sn1, m);
            sn2 += __shfl_xor(sn2, m);
            sn3 += __shfl_xor(sn3, m);
            sn4 += __shfl_xor(sn4, m);
        }

        // --- clip + -log_sigmoid ---
        sp  = fminf(fmaxf(sp,  -CLIPV), CLIPV);
        sn0 = fminf(fmaxf(sn0, -CLIPV), CLIPV);
        sn1 = fminf(fmaxf(sn1, -CLIPV), CLIPV);
        sn2 = fminf(fmaxf(sn2, -CLIPV), CLIPV);
        sn3 = fminf(fmaxf(sn3, -CLIPV), CLIPV);
        sn4 = fminf(fmaxf(sn4, -CLIPV), CLIPV);
        acc  = __logf(1.0f + __expf(-sp));    // positive: -log_sigmoid(+s)
        acc += __logf(1.0f + __expf(sn0));    // negative: -log_sigmoid(-s)
        acc += __logf(1.0f + __expf(sn1));
        acc += __logf(1.0f + __expf(sn2));
        acc += __logf(1.0f + __expf(sn3));
        acc += __logf(1.0f + __expf(sn4));
    }

    // Fold across the wave: xor 8/16/32 combines exactly one lane from each of
    // the 8 groups (fixed lane&7) -> each group counted exactly once.
    float t = acc;
    t += __shfl_xor(t, 8);
    t += __shfl_xor(t, 16);
    t += __shfl_xor(t, 32);
    __shared__ float smem[TPB / 64];
    if ((threadIdx.x & 63) == 0) smem[threadIdx.x >> 6] = t;
    __syncthreads();
    if (threadIdx.x == 0) {
        float s = 0.0f;
#pragma unroll
        for (int i = 0; i < TPB / 64; ++i) s += smem[i];
        partial[blockIdx.x] = s;             // plain store, no atomics
    }
}

// Stage 2: one 256-thread block reduces n partials, WRITES out[0].
__global__ void __launch_bounds__(256) sg_reduce(
    const float* __restrict__ partial, int n, float* __restrict__ out)
{
    float t = 0.0f;
    for (int i = threadIdx.x; i < n; i += 256) t += partial[i];
    t += __shfl_xor(t, 1);
    t += __shfl_xor(t, 2);
    t += __shfl_xor(t, 4);
    t += __shfl_xor(t, 8);
    t += __shfl_xor(t, 16);
    t += __shfl_xor(t, 32);
    __shared__ float smem[4];
    if ((threadIdx.x & 63) == 0) smem[threadIdx.x >> 6] = t;
    __syncthreads();
    if (threadIdx.x == 0) out[0] = smem[0] + smem[1] + smem[2] + smem[3];
}

extern "C" void kernel_launch(void* const* d_in, const int* in_sizes, int n_in,
                              void* d_out, int out_size, void* d_ws, size_t ws_size,
                              hipStream_t stream) {
    const float* u_emb = (const float*)d_in[0];
    const float* v_emb = (const float*)d_in[1];
    const int*   nodes = (const int*)d_in[2];
    const int*   posu  = (const int*)d_in[3];
    const int*   posv  = (const int*)d_in[4];
    const int*   negu  = (const int*)d_in[5];
    const int*   negv  = (const int*)d_in[6];
    const int n_pos = in_sizes[3];           // 24640 = 770 * 32

    float* partial = (float*)d_ws;
    float* out     = (float*)d_out;

    const int blocks = (n_pos + 31) / 32;    // 770
    sg_fused_partial<<<blocks, TPB, 0, stream>>>(
        u_emb, v_emb, nodes, posu, posv, negu, negv, n_pos, partial);
    sg_reduce<<<1, 256, 0, stream>>>(partial, blocks, out);
}

// Round 6
// 13.998 us; speedup vs baseline: 1.2928x; 1.2928x over previous
//
#include <hip/hip_runtime.h>

#define DIM 128
#define TPB 256
#define CLIPV 6.0f

__device__ __forceinline__ float dot4(const float4 a, const float4 b) {
    return a.x * b.x + a.y * b.y + a.z * b.z + a.w * b.w;
}

// One 16-lane group = pos pair g (1 dot) + neg bundle g (5 dots sharing the
// center u-row; negu = repeat(posv,5) structurally). lane covers 8 elems
// (2 float4) of each 128-dim row -> 64 data floats live per lane (vs 116 in
// the 8-lane version) for occupancy. Exact grid: n_pos/16 blocks, no loop.
__global__ void __launch_bounds__(TPB) sg_fused_partial(
    const float* __restrict__ u_emb,
    const float* __restrict__ v_emb,
    const int*  __restrict__ nodes,
    const int*  __restrict__ posu,
    const int*  __restrict__ posv,
    const int*  __restrict__ negu,
    const int*  __restrict__ negv,
    int n_pos,
    float* __restrict__ partial)
{
    const int lane = threadIdx.x & 15;       // 0..15 within group
    const int grp  = threadIdx.x >> 4;       // 0..15 groups per block
    const int g    = blockIdx.x * 16 + grp;  // pos-pair id == neg-bundle id

    float acc = 0.0f;
    if (g < n_pos) {
        const int iu = posu[g];
        const int iv = posv[g];
        const int ic = negu[5 * g];          // bundle center (== posv[g])
        const int nu = nodes[iu];
        const int nv = nodes[iv];
        const int nc = nodes[ic];
        const int nn0 = nodes[negv[5 * g + 0]];
        const int nn1 = nodes[negv[5 * g + 1]];
        const int nn2 = nodes[negv[5 * g + 2]];
        const int nn3 = nodes[negv[5 * g + 3]];
        const int nn4 = nodes[negv[5 * g + 4]];

        const int off = lane * 8;            // 8 floats per lane
        const float4* pa = reinterpret_cast<const float4*>(u_emb + (unsigned)nu * DIM + off);
        const float4* pb = reinterpret_cast<const float4*>(v_emb + (unsigned)nv * DIM + off);
        const float4* pc = reinterpret_cast<const float4*>(u_emb + (unsigned)nc * DIM + off);
        const float4* p0 = reinterpret_cast<const float4*>(v_emb + (unsigned)nn0 * DIM + off);
        const float4* p1 = reinterpret_cast<const float4*>(v_emb + (unsigned)nn1 * DIM + off);
        const float4* p2 = reinterpret_cast<const float4*>(v_emb + (unsigned)nn2 * DIM + off);
        const float4* p3 = reinterpret_cast<const float4*>(v_emb + (unsigned)nn3 * DIM + off);
        const float4* p4 = reinterpret_cast<const float4*>(v_emb + (unsigned)nn4 * DIM + off);

        const float4 a0 = pa[0], a1 = pa[1];
        const float4 b0 = pb[0], b1 = pb[1];
        const float4 c0 = pc[0], c1 = pc[1];
        const float4 d00 = p0[0], d01 = p0[1];
        const float4 d10 = p1[0], d11 = p1[1];
        const float4 d20 = p2[0], d21 = p2[1];
        const float4 d30 = p3[0], d31 = p3[1];
        const float4 d40 = p4[0], d41 = p4[1];

        float sp  = dot4(a0, b0)  + dot4(a1, b1);
        float sn0 = dot4(c0, d00) + dot4(c1, d01);
        float sn1 = dot4(c0, d10) + dot4(c1, d11);
        float sn2 = dot4(c0, d20) + dot4(c1, d21);
        float sn3 = dot4(c0, d30) + dot4(c1, d31);
        float sn4 = dot4(c0, d40) + dot4(c1, d41);

        // 16-lane butterfly for the 6 sums
#pragma unroll
        for (int m = 1; m <= 8; m <<= 1) {
            sp  += __shfl_xor(sp,  m);
            sn0 += __shfl_xor(sn0, m);
            sn1 += __shfl_xor(sn1, m);
            sn2 += __shfl_xor(sn2, m);
            sn3 += __shfl_xor(sn3, m);
            sn4 += __shfl_xor(sn4, m);
        }

        sp  = fminf(fmaxf(sp,  -CLIPV), CLIPV);
        sn0 = fminf(fmaxf(sn0, -CLIPV), CLIPV);
        sn1 = fminf(fmaxf(sn1, -CLIPV), CLIPV);
        sn2 = fminf(fmaxf(sn2, -CLIPV), CLIPV);
        sn3 = fminf(fmaxf(sn3, -CLIPV), CLIPV);
        sn4 = fminf(fmaxf(sn4, -CLIPV), CLIPV);
        acc  = __logf(1.0f + __expf(-sp));   // positive: -log_sigmoid(+s)
        acc += __logf(1.0f + __expf(sn0));   // negatives: -log_sigmoid(-s)
        acc += __logf(1.0f + __expf(sn1));
        acc += __logf(1.0f + __expf(sn2));
        acc += __logf(1.0f + __expf(sn3));
        acc += __logf(1.0f + __expf(sn4));
    }

    // Fold the wave's 4 groups: lanes l, l^16, l^32, l^48 have fixed lane&15
    // -> each group counted exactly once.
    float t = acc;
    t += __shfl_xor(t, 16);
    t += __shfl_xor(t, 32);
    __shared__ float smem[TPB / 64];
    if ((threadIdx.x & 63) == 0) smem[threadIdx.x >> 6] = t;
    __syncthreads();
    if (threadIdx.x == 0) {
        float s = 0.0f;
#pragma unroll
        for (int i = 0; i < TPB / 64; ++i) s += smem[i];
        partial[blockIdx.x] = s;             // plain store, no atomics
    }
}

// Stage 2: one 256-thread block reduces n partials, WRITES out[0].
__global__ void __launch_bounds__(256) sg_reduce(
    const float* __restrict__ partial, int n, float* __restrict__ out)
{
    float t = 0.0f;
    for (int i = threadIdx.x; i < n; i += 256) t += partial[i];
    t += __shfl_xor(t, 1);
    t += __shfl_xor(t, 2);
    t += __shfl_xor(t, 4);
    t += __shfl_xor(t, 8);
    t += __shfl_xor(t, 16);
    t += __shfl_xor(t, 32);
    __shared__ float smem[4];
    if ((threadIdx.x & 63) == 0) smem[threadIdx.x >> 6] = t;
    __syncthreads();
    if (threadIdx.x == 0) out[0] = smem[0] + smem[1] + smem[2] + smem[3];
}

extern "C" void kernel_launch(void* const* d_in, const int* in_sizes, int n_in,
                              void* d_out, int out_size, void* d_ws, size_t ws_size,
                              hipStream_t stream) {
    const float* u_emb = (const float*)d_in[0];
    const float* v_emb = (const float*)d_in[1];
    const int*   nodes = (const int*)d_in[2];
    const int*   posu  = (const int*)d_in[3];
    const int*   posv  = (const int*)d_in[4];
    const int*   negu  = (const int*)d_in[5];
    const int*   negv  = (const int*)d_in[6];
    const int n_pos = in_sizes[3];           // 24640 = 1540 * 16

    float* partial = (float*)d_ws;
    float* out     = (float*)d_out;

    const int blocks = (n_pos + 15) / 16;    // 1540
    sg_fused_partial<<<blocks, TPB, 0, stream>>>(
        u_emb, v_emb, nodes, posu, posv, negu, negv, n_pos, partial);
    sg_reduce<<<1, 256, 0, stream>>>(partial, blocks, out);
}